// Round 6
// baseline (48.856 us; speedup 1.0000x reference)
//
#include <hip/hip_runtime.h>

// SigmoidLoss: out = sum_n mean_{s,t} [ softplus(z) - W[s,t]*z ],  z = f1[n,s]*f2[n,t]
// f1[n,s] = emb[bi, s, ei], f2[n,s] = emb[32+bi, s, ei],  n = bi*64 + ei
// W banded: W[s,t] = 1 - q/20, q = (t>=s ? t-s : s-t-1), zero for q >= 20.
//
// TRANS-FREE softplus: softplus(z) = z/2 + L(z/2), L(x) = ln(2 cosh x) (even!)
//   L(|z|/2) ~= P(y), y = z^2, deg-6 Chebyshev interpolant on y in [0,16]
//   (|z| <= 4), max err ~5e-5. For |z| > 4: max(|z|/2, P(y)) -> P dives below
//   |z|/2 (verified t=1.5..5), returning the exact asymptote x (missing only
//   log1p(e^-|z|) <= 0.018 on ~0.6% of elems -> output bias ~0.1 << 32.6 thr).
// Evaluated in packed FP32 (v_pk_fma_f32 / v_pk_mul_f32, full-rate on CDNA).

#define SIDE 256
#define NB 32
#define NE 64
#define NROWS (NB * NE)  // 2048

typedef float v2f __attribute__((ext_vector_type(2)));

__device__ __forceinline__ v2f pk_fma(v2f a, v2f b, v2f c) {
    v2f d;
    asm("v_pk_fma_f32 %0, %1, %2, %3" : "=v"(d) : "v"(a), "v"(b), "v"(c));
    return d;
}
__device__ __forceinline__ v2f pk_mul(v2f a, v2f b) {
    v2f d;
    asm("v_pk_mul_f32 %0, %1, %2" : "=v"(d) : "v"(a), "v"(b));
    return d;
}

// P(t), t = y/8 - 1: power-basis coeffs of deg-6 Chebyshev interpolant of
// ln(2cosh(sqrt(y)/2)) on y in [0,16]. Verified: P(-1)=ln2, P(0)=L(sqrt8/2),
// P(0.5)=L(sqrt12/2), P(1)=2.0181499 (all 7-digit exact).
#define PC0 1.47164001f
#define PC1 0.62832255f
#define PC2 -0.10441402f
#define PC3 0.02925480f
#define PC4 -0.00971952f
#define PC5 0.00492400f
#define PC6 -0.00185792f

__global__ __launch_bounds__(256) void sigloss_main(const float* __restrict__ emb,
                                                    float* __restrict__ partial) {
    const int n   = blockIdx.x;
    const int bi  = n >> 6;
    const int ei  = n & 63;
    const int tid = threadIdx.x;  // 0..255

    // pk[j] = { f1[2j]^2, f1[2j+1]^2, f1[2j], f1[2j+1] }
    __shared__ float4 pk[SIDE / 2];
    __shared__ float  f2s[SIDE];

    const float a = emb[(size_t)bi * (SIDE * NE) + (size_t)tid * NE + ei];
    const float b = emb[(size_t)(NB + bi) * (SIDE * NE) + (size_t)tid * NE + ei];
    {
        float* base = (float*)&pk[tid >> 1];
        base[tid & 1]       = a * a;
        base[2 + (tid & 1)] = a;
    }
    f2s[tid] = b;
    __syncthreads();

    // ---- banded W-term: thread owns row s = tid (f1[s] = a in register) ----
    float g = 0.0f;
    {
        const int s  = tid;
        const int t0 = (s - 20 > 0) ? (s - 20) : 0;
        const int t1 = (s + 20 < SIDE) ? (s + 20) : SIDE;
        for (int t = t0; t < t1; ++t) {
            int d = t - s;
            int q = d ^ (d >> 31);   // d>=0 ? d : -d-1
            g = fmaf(1.0f - 0.05f * (float)q, f2s[t], g);
        }
    }
    const float wterm = a * g;

    // ---- softplus term: thread owns column t = tid, c = f2[t] ----
    const float c = b;
    const v2f csq2 = {c * c, c * c};
    const v2f ch2  = {0.5f * c, 0.5f * c};
    const v2f k18  = {0.125f, 0.125f};
    const v2f km1  = {-1.0f, -1.0f};
    const v2f c6 = {PC6, PC6}, c5 = {PC5, PC5}, c4 = {PC4, PC4}, c3 = {PC3, PC3},
              c2 = {PC2, PC2}, c1 = {PC1, PC1}, c0 = {PC0, PC0};

    v2f accz = {0.0f, 0.0f};
    v2f accr = {0.0f, 0.0f};
    #pragma unroll 8
    for (int j = 0; j < SIDE / 2; ++j) {
        const float4 P = pk[j];
        const v2f sq  = {P.x, P.y};
        const v2f f1p = {P.z, P.w};
        const v2f y = pk_mul(sq, csq2);          // y = z^2
        const v2f t = pk_fma(y, k18, km1);       // t = y/8 - 1
        v2f h = pk_fma(c6, t, c5);
        h = pk_fma(h, t, c4);
        h = pk_fma(h, t, c3);
        h = pk_fma(h, t, c2);
        h = pk_fma(h, t, c1);
        h = pk_fma(h, t, c0);                    // h ~= L(|z|/2) on |z|<=4
        const v2f p = pk_mul(f1p, ch2);          // p = z/2
        accz += p;
        v2f r;
        r.x = fmaxf(fabsf(p.x), h.x);            // max(|z|/2, P)
        r.y = fmaxf(fabsf(p.y), h.y);
        accr += r;
    }
    float val = (accz.x + accz.y) + (accr.x + accr.y) - wterm;

    // ---- block reduction (4 waves of 64) ----
    for (int off = 32; off > 0; off >>= 1) val += __shfl_down(val, off, 64);
    __shared__ float wsum[4];
    if ((tid & 63) == 0) wsum[tid >> 6] = val;
    __syncthreads();
    if (tid == 0) partial[n] = wsum[0] + wsum[1] + wsum[2] + wsum[3];
}

__global__ __launch_bounds__(256) void sigloss_reduce(const float* __restrict__ partial,
                                                      float* __restrict__ out) {
    const int tid = threadIdx.x;
    float v = 0.0f;
    #pragma unroll
    for (int i = tid; i < NROWS; i += 256) v += partial[i];
    for (int off = 32; off > 0; off >>= 1) v += __shfl_down(v, off, 64);
    __shared__ float wsum[4];
    if ((tid & 63) == 0) wsum[tid >> 6] = v;
    __syncthreads();
    if (tid == 0) out[0] = (wsum[0] + wsum[1] + wsum[2] + wsum[3]) * (1.0f / 65536.0f);
}

extern "C" void kernel_launch(void* const* d_in, const int* in_sizes, int n_in,
                              void* d_out, int out_size, void* d_ws, size_t ws_size,
                              hipStream_t stream) {
    const float* emb = (const float*)d_in[0];   // (64,256,64) f32
    float* partial = (float*)d_ws;              // 2048 floats scratch
    float* out = (float*)d_out;                 // 1 float
    sigloss_main<<<NROWS, 256, 0, stream>>>(emb, partial);
    sigloss_reduce<<<1, 256, 0, stream>>>(partial, out);
}

// Round 7
// 35.473 us; speedup vs baseline: 1.3773x; 1.3773x over previous
//
#include <hip/hip_runtime.h>

// SigmoidLoss: out = sum_n mean_{s,t} [ softplus(z) - W[s,t]*z ],  z = f1[n,s]*f2[n,t]
// f1[n,s] = emb[bi, s, ei], f2[n,s] = emb[32+bi, s, ei],  n = bi*64 + ei
// W banded: W[s,t] = 1 - q/20, q = (t>=s ? t-s : s-t-1), zero for q >= 20.
//
// Pipeline:
//  K1 transpose: emb -> f1T[n][s] (*log2e) and f2T[n][s], both contiguous.
//     Coalesced reads (lane=ei) + LDS 64x65 tile + coalesced writes (lane=s).
//  K2 main: f1 row fetched via the SCALAR pipe (wave-uniform index -> s_load),
//     so the softplus inner loop issues ZERO LDS instructions; f2 staged in
//     LDS only for the banded W-term (40 reads/thread).
//     softplus(z) = ln2*log2(1+exp2(x)), x = z*log2e clamped <= 14.5 so an
//     8-factor product of (1+e) stays finite: ONE v_log_f32 per 8 elements.
//     Clamp perturbs only |z|>10.05 (P~1e-5, bias ~0.06 << 32.6 threshold).
//  K3 reduce: 2048 partials -> scalar.

#define SIDE 256
#define NB 32
#define NE 64
#define NROWS (NB * NE)  // 2048
#define LOG2E 1.4426950408889634f
#define LN2 0.6931471805599453f

__global__ __launch_bounds__(256) void sig_transpose(const float* __restrict__ emb,
                                                     float* __restrict__ f1T,
                                                     float* __restrict__ f2T) {
    const int b    = blockIdx.x;   // 0..255
    const int bi   = b >> 2;       // 0..63 (both halves)
    const int st   = b & 3;        // s-tile
    const int s0   = st * 64;
    const int tid  = threadIdx.x;
    const int lane = tid & 63;
    const int grp  = tid >> 6;     // 0..3

    __shared__ float tile[64][65];
    #pragma unroll
    for (int k = 0; k < 16; ++k) {
        const int r = grp + 4 * k;  // 0..63
        tile[r][lane] = emb[(size_t)bi * (SIDE * NE) + (size_t)(s0 + r) * NE + lane];
    }
    __syncthreads();
    #pragma unroll
    for (int k = 0; k < 16; ++k) {
        const int e = grp + 4 * k;          // ei 0..63
        const float v = tile[lane][e];      // stride-65: conflict-free
        if (bi < NB) f1T[(size_t)(bi * NE + e) * SIDE + s0 + lane] = v * LOG2E;
        else         f2T[(size_t)((bi - NB) * NE + e) * SIDE + s0 + lane] = v;
    }
}

__global__ __launch_bounds__(256) void sigloss_main(const float* __restrict__ f1T,
                                                    const float* __restrict__ f2T,
                                                    float* __restrict__ partial) {
    const int n   = blockIdx.x;
    const int tid = threadIdx.x;  // 0..255
    const float* __restrict__ row = f1T + (size_t)n * SIDE;  // wave-uniform base

    const float c    = f2T[(size_t)n * SIDE + tid];  // coalesced
    const float myf1 = row[tid];                     // coalesced (per-lane)
    __shared__ float f2s[SIDE];
    f2s[tid] = c;
    __syncthreads();

    // ---- banded W-term: thread owns row s = tid (only LDS consumer) ----
    float g = 0.0f;
    {
        const int s  = tid;
        const int t0 = (s - 20 > 0) ? (s - 20) : 0;
        const int t1 = (s + 20 < SIDE) ? (s + 20) : SIDE;
        for (int t = t0; t < t1; ++t) {
            int d = t - s;
            int q = d ^ (d >> 31);   // d>=0 ? d : -d-1
            g = fmaf(1.0f - 0.05f * (float)q, f2s[t], g);
        }
    }

    // ---- softplus: f1 row arrives via s_load (uniform index), c in VGPR ----
    float acc = 0.0f;
    #pragma unroll 2
    for (int s8 = 0; s8 < SIDE; s8 += 8) {
        const float x0 = row[s8 + 0] * c;
        const float x1 = row[s8 + 1] * c;
        const float x2 = row[s8 + 2] * c;
        const float x3 = row[s8 + 3] * c;
        const float x4 = row[s8 + 4] * c;
        const float x5 = row[s8 + 5] * c;
        const float x6 = row[s8 + 6] * c;
        const float x7 = row[s8 + 7] * c;
        const float e0 = __builtin_amdgcn_exp2f(fminf(x0, 14.5f));
        const float e1 = __builtin_amdgcn_exp2f(fminf(x1, 14.5f));
        const float e2 = __builtin_amdgcn_exp2f(fminf(x2, 14.5f));
        const float e3 = __builtin_amdgcn_exp2f(fminf(x3, 14.5f));
        const float e4 = __builtin_amdgcn_exp2f(fminf(x4, 14.5f));
        const float e5 = __builtin_amdgcn_exp2f(fminf(x5, 14.5f));
        const float e6 = __builtin_amdgcn_exp2f(fminf(x6, 14.5f));
        const float e7 = __builtin_amdgcn_exp2f(fminf(x7, 14.5f));
        const float p01 = (1.0f + e0) * (1.0f + e1);
        const float p23 = (1.0f + e2) * (1.0f + e3);
        const float p45 = (1.0f + e4) * (1.0f + e5);
        const float p67 = (1.0f + e6) * (1.0f + e7);
        acc += __builtin_amdgcn_logf((p01 * p23) * (p45 * p67));
    }
    // true wterm = (myf1*ln2)*g ; val = ln2*acc - wterm = ln2*(acc - myf1*g)
    float val = (acc - myf1 * g) * LN2;

    // ---- block reduction (4 waves of 64) ----
    for (int off = 32; off > 0; off >>= 1) val += __shfl_down(val, off, 64);
    __shared__ float wsum[4];
    if ((tid & 63) == 0) wsum[tid >> 6] = val;
    __syncthreads();
    if (tid == 0) partial[n] = wsum[0] + wsum[1] + wsum[2] + wsum[3];
}

__global__ __launch_bounds__(256) void sigloss_reduce(const float* __restrict__ partial,
                                                      float* __restrict__ out) {
    const int tid = threadIdx.x;
    float v = 0.0f;
    #pragma unroll
    for (int i = tid; i < NROWS; i += 256) v += partial[i];
    for (int off = 32; off > 0; off >>= 1) v += __shfl_down(v, off, 64);
    __shared__ float wsum[4];
    if ((tid & 63) == 0) wsum[tid >> 6] = v;
    __syncthreads();
    if (tid == 0) out[0] = (wsum[0] + wsum[1] + wsum[2] + wsum[3]) * (1.0f / 65536.0f);
}

extern "C" void kernel_launch(void* const* d_in, const int* in_sizes, int n_in,
                              void* d_out, int out_size, void* d_ws, size_t ws_size,
                              hipStream_t stream) {
    const float* emb = (const float*)d_in[0];   // (64,256,64) f32
    float* f1T     = (float*)d_ws;                             // 2 MB
    float* f2T     = (float*)((char*)d_ws + (size_t)NROWS * SIDE * 4);      // 2 MB
    float* partial = (float*)((char*)d_ws + (size_t)2 * NROWS * SIDE * 4);  // 8 KB
    float* out = (float*)d_out;

    sig_transpose<<<256, 256, 0, stream>>>(emb, f1T, f2T);
    sigloss_main<<<NROWS, 256, 0, stream>>>(f1T, f2T, partial);
    sigloss_reduce<<<1, 256, 0, stream>>>(partial, out);
}

// Round 8
// 20.156 us; speedup vs baseline: 2.4239x; 1.7600x over previous
//
#include <hip/hip_runtime.h>

// SigmoidLoss: out = sum_n mean_{s,t} [ softplus(z) - W[s,t]*z ],  z = f1[n,s]*f2[n,t]
// f1[n,s] = emb[bi, s, ei], f2[n,s] = emb[32+bi, s, ei],  n = bi*64 + ei
// W banded: W[s,t] = 1 - q/20, q = (t>=s ? t-s : s-t-1), zero for q >= 20.
//
// WORK REDUCTION (4x): for fixed n, sum_s softplus(f1[s]*c) =: G(c) is a
// smooth 1-D function. Build a 64-node piecewise-linear table of G on
// c in [-6,6] (64x256 exact softplus evals instead of 256x256), then each
// thread t evaluates G(f2[t]) by ONE linear interpolation. PWL error on the
// convex G: h=0.19, G''<=~64 -> <=0.28 per eval -> output bias ~1.4 << 32.6.
// |c|>6 (P~1e-9/elem) extrapolates the end segment = G's asymptote. Exact
// softplus in build: ln2*log2(1+exp2(x)), x clamped <=14.5, ONE v_log_f32
// per 8 elems (8-factor product < 2^117, finite).
//
// LDS layout: f1 padded stride-68 (68%32=4 -> the 4 part-blocks start in
// distinct banks; 68*4B = 16B-aligned -> ds_read_b128). In the build, lanes
// with equal part read the same address (broadcast), 4 distinct addresses
// hit 4 distinct banks: conflict-free.

#define SIDE 256
#define NB 32
#define NE 64
#define NROWS (NB * NE)  // 2048
#define LOG2E 1.4426950408889634f
#define LN2 0.6931471805599453f
#define NODES 64
#define CRANGE 6.0f
#define HSTEP 0.1904761905f           // 12/63
#define USCALE 5.25f                  // 63/12

__global__ __launch_bounds__(256) void sigloss_main(const float* __restrict__ emb,
                                                    float* __restrict__ partial) {
    const int n   = blockIdx.x;
    const int bi  = n >> 6;
    const int ei  = n & 63;
    const int tid = threadIdx.x;  // 0..255

    __shared__ __align__(16) float f1pad[272];  // stride-68 blocks of 64
    __shared__ float f2s[SIDE];
    __shared__ float table[NODES];
    __shared__ float wsum[4];

    const float a = emb[(size_t)bi * (SIDE * NE) + (size_t)tid * NE + ei];
    const float c = emb[(size_t)(NB + bi) * (SIDE * NE) + (size_t)tid * NE + ei];
    f1pad[tid + 4 * (tid >> 6)] = a;   // = 68*(tid>>6) + (tid&63)
    f2s[tid] = c;
    __syncthreads();

    // ---- build G table: node = tid>>2 (64 nodes), part = tid&3 (64 s each) ----
    {
        const int node = tid >> 2;
        const int p    = tid & 3;
        const float ckl = (-CRANGE + (float)node * HSTEP) * LOG2E;
        const float4* fp = (const float4*)&f1pad[68 * p];
        float acc = 0.0f;
        #pragma unroll
        for (int i4 = 0; i4 < 16; i4 += 2) {
            const float4 A = fp[i4];
            const float4 B = fp[i4 + 1];
            const float e0 = __builtin_amdgcn_exp2f(fminf(A.x * ckl, 14.5f));
            const float e1 = __builtin_amdgcn_exp2f(fminf(A.y * ckl, 14.5f));
            const float e2 = __builtin_amdgcn_exp2f(fminf(A.z * ckl, 14.5f));
            const float e3 = __builtin_amdgcn_exp2f(fminf(A.w * ckl, 14.5f));
            const float e4 = __builtin_amdgcn_exp2f(fminf(B.x * ckl, 14.5f));
            const float e5 = __builtin_amdgcn_exp2f(fminf(B.y * ckl, 14.5f));
            const float e6 = __builtin_amdgcn_exp2f(fminf(B.z * ckl, 14.5f));
            const float e7 = __builtin_amdgcn_exp2f(fminf(B.w * ckl, 14.5f));
            const float p01 = (1.0f + e0) * (1.0f + e1);
            const float p23 = (1.0f + e2) * (1.0f + e3);
            const float p45 = (1.0f + e4) * (1.0f + e5);
            const float p67 = (1.0f + e6) * (1.0f + e7);
            acc += __builtin_amdgcn_logf((p01 * p23) * (p45 * p67));
        }
        acc += __shfl_xor(acc, 1, 64);
        acc += __shfl_xor(acc, 2, 64);
        if (p == 0) table[node] = acc * LN2;
    }
    __syncthreads();

    // ---- banded W-term: thread owns row s = tid (f1[s] = a in register) ----
    float g = 0.0f;
    {
        const int s  = tid;
        const int t0 = (s - 20 > 0) ? (s - 20) : 0;
        const int t1 = (s + 20 < SIDE) ? (s + 20) : SIDE;
        for (int t = t0; t < t1; ++t) {
            int d = t - s;
            int q = d ^ (d >> 31);   // d>=0 ? d : -d-1
            g = fmaf(1.0f - 0.05f * (float)q, f2s[t], g);
        }
    }

    // ---- softplus column-sum for t = tid: ONE table interpolation ----
    const float u  = (c + CRANGE) * USCALE;
    int jj = (int)floorf(u);
    jj = (jj < 0) ? 0 : ((jj > NODES - 2) ? (NODES - 2) : jj);
    const float frac = u - (float)jj;          // <0 / >1 extrapolates (asymptote)
    const float Tj  = table[jj];
    const float Tj1 = table[jj + 1];
    float val = fmaf(frac, Tj1 - Tj, Tj) - a * g;

    // ---- block reduction (4 waves of 64) ----
    for (int off = 32; off > 0; off >>= 1) val += __shfl_down(val, off, 64);
    if ((tid & 63) == 0) wsum[tid >> 6] = val;
    __syncthreads();
    if (tid == 0) partial[n] = wsum[0] + wsum[1] + wsum[2] + wsum[3];
}

__global__ __launch_bounds__(256) void sigloss_reduce(const float* __restrict__ partial,
                                                      float* __restrict__ out) {
    const int tid = threadIdx.x;
    float v = 0.0f;
    #pragma unroll
    for (int i = tid; i < NROWS; i += 256) v += partial[i];
    for (int off = 32; off > 0; off >>= 1) v += __shfl_down(v, off, 64);
    __shared__ float wsum[4];
    if ((tid & 63) == 0) wsum[tid >> 6] = v;
    __syncthreads();
    if (tid == 0) out[0] = (wsum[0] + wsum[1] + wsum[2] + wsum[3]) * (1.0f / 65536.0f);
}

extern "C" void kernel_launch(void* const* d_in, const int* in_sizes, int n_in,
                              void* d_out, int out_size, void* d_ws, size_t ws_size,
                              hipStream_t stream) {
    const float* emb = (const float*)d_in[0];   // (64,256,64) f32
    float* partial = (float*)d_ws;              // 2048 floats scratch
    float* out = (float*)d_out;                 // 1 float
    sigloss_main<<<NROWS, 256, 0, stream>>>(emb, partial);
    sigloss_reduce<<<1, 256, 0, stream>>>(partial, out);
}

// Round 9
// 14.977 us; speedup vs baseline: 3.2621x; 1.3458x over previous
//
#include <hip/hip_runtime.h>

// SigmoidLoss: out = sum_n mean_{s,t} [ softplus(z) - W[s,t]*z ],  z = f1[n,s]*f2[n,t]
// f1[n,s] = emb[bi, s, ei], f2[n,s] = emb[32+bi, s, ei],  n = bi*64 + ei
// W banded: W[s,t] = 1-0.05q, q = (t>=s ? t-s : s-t-1), zero for q >= 20.
//
// G-table (4x->8x work cut): G(c) = sum_s softplus(f1[s]*c) tabulated at 32
// nodes on c in [-6,6] (32x256 exact evals), each thread then does one
// 3-point quadratic interpolation: err ~ h^3*G''' ~ 0.1 -> output bias << 1.
// Exact softplus in build: ln2*log2(1+exp2(x)), x clamped <= 14.5; ONE
// v_log_f32 per 8 elems (8-factor product < 2^117 finite).
//
// W-term via prefix sums (kills the 40-iter LDS loop): with exclusive
// prefixes P0 = sum f2, P1 = sum t*f2 over t < k:
//   row s: left  = (1.05-0.05s)*(P0[s]-P0[t0]) + 0.05*(P1[s]-P1[t0])
//          right = (1.00+0.05s)*(P0[t1]-P0[s]) - 0.05*(P1[t1]-P1[s])
// t0 = max(s-20,0), t1 = min(s+20,256). Exact decomposition of the band.

#define SIDE 256
#define NB 32
#define NE 64
#define NROWS (NB * NE)  // 2048
#define LOG2E 1.4426950408889634f
#define LN2 0.6931471805599453f
#define NODES 32
#define CRANGE 6.0f
#define HSTEP (12.0f / 31.0f)
#define USCALE (31.0f / 12.0f)

__global__ __launch_bounds__(256) void sigloss_main(const float* __restrict__ emb,
                                                    float* __restrict__ partial) {
    const int n   = blockIdx.x;
    const int bi  = n >> 6;
    const int ei  = n & 63;
    const int tid = threadIdx.x;  // 0..255
    const int w   = tid >> 6;     // wave 0..3
    const int lane = tid & 63;

    // f1 in 8 part-blocks of 32, stride 36 (36*4B=144B: 16B-aligned, part
    // bases hit banks 4p -> 8 distinct banks; broadcast within 8-lane groups).
    __shared__ __align__(16) float f1pad[8 * 36 - 4];  // 284
    __shared__ float P0arr[SIDE + 1];
    __shared__ float P1arr[SIDE + 1];
    __shared__ float table[NODES];
    __shared__ float wt0[4], wt1[4];
    __shared__ float wsum[4];

    const float a = emb[(size_t)bi * (SIDE * NE) + (size_t)tid * NE + ei];
    const float c = emb[(size_t)(NB + bi) * (SIDE * NE) + (size_t)tid * NE + ei];
    f1pad[36 * (tid >> 5) + (tid & 31)] = a;

    // ---- wave-level inclusive scans of f2 and t*f2 ----
    float v0 = c;
    float v1 = (float)tid * c;
    #pragma unroll
    for (int off = 1; off < 64; off <<= 1) {
        const float u0 = __shfl_up(v0, off, 64);
        const float u1 = __shfl_up(v1, off, 64);
        if (lane >= off) { v0 += u0; v1 += u1; }
    }
    if (lane == 63) { wt0[w] = v0; wt1[w] = v1; }
    __syncthreads();

    float off0 = 0.0f, off1 = 0.0f;
    for (int w2 = 0; w2 < w; ++w2) { off0 += wt0[w2]; off1 += wt1[w2]; }
    P0arr[tid + 1] = v0 + off0;
    P1arr[tid + 1] = v1 + off1;
    if (tid == 0) { P0arr[0] = 0.0f; P1arr[0] = 0.0f; }

    // ---- build G table: node = tid>>3 (32 nodes), part = tid&7 (32 s each) ----
    {
        const int node = tid >> 3;
        const int p    = tid & 7;
        const float ckl = (-CRANGE + (float)node * HSTEP) * LOG2E;
        const float4* fp = (const float4*)&f1pad[36 * p];
        float acc = 0.0f;
        #pragma unroll
        for (int i4 = 0; i4 < 8; i4 += 2) {
            const float4 A = fp[i4];
            const float4 B = fp[i4 + 1];
            const float e0 = __builtin_amdgcn_exp2f(fminf(A.x * ckl, 14.5f));
            const float e1 = __builtin_amdgcn_exp2f(fminf(A.y * ckl, 14.5f));
            const float e2 = __builtin_amdgcn_exp2f(fminf(A.z * ckl, 14.5f));
            const float e3 = __builtin_amdgcn_exp2f(fminf(A.w * ckl, 14.5f));
            const float e4 = __builtin_amdgcn_exp2f(fminf(B.x * ckl, 14.5f));
            const float e5 = __builtin_amdgcn_exp2f(fminf(B.y * ckl, 14.5f));
            const float e6 = __builtin_amdgcn_exp2f(fminf(B.z * ckl, 14.5f));
            const float e7 = __builtin_amdgcn_exp2f(fminf(B.w * ckl, 14.5f));
            const float p01 = (1.0f + e0) * (1.0f + e1);
            const float p23 = (1.0f + e2) * (1.0f + e3);
            const float p45 = (1.0f + e4) * (1.0f + e5);
            const float p67 = (1.0f + e6) * (1.0f + e7);
            acc += __builtin_amdgcn_logf((p01 * p23) * (p45 * p67));
        }
        acc += __shfl_xor(acc, 1, 64);
        acc += __shfl_xor(acc, 2, 64);
        acc += __shfl_xor(acc, 4, 64);
        if ((tid & 7) == 0) table[node] = acc * LN2;
    }
    __syncthreads();

    // ---- W-term for row s = tid via prefix sums ----
    const int s  = tid;
    const int t0 = (s - 20 > 0) ? (s - 20) : 0;
    const int t1 = (s + 20 < SIDE) ? (s + 20) : SIDE;
    const float P0t0 = P0arr[t0], P0s = P0arr[s], P0t1 = P0arr[t1];
    const float P1t0 = P1arr[t0], P1s = P1arr[s], P1t1 = P1arr[t1];
    const float sf = (float)s;
    const float left  = (1.05f - 0.05f * sf) * (P0s - P0t0) + 0.05f * (P1s - P1t0);
    const float right = (1.0f + 0.05f * sf) * (P0t1 - P0s) - 0.05f * (P1t1 - P1s);
    const float wterm = a * (left + right);

    // ---- G(c) by quadratic interpolation ----
    const float u = (c + CRANGE) * USCALE;
    int j = (int)floorf(u + 0.5f);
    j = (j < 1) ? 1 : ((j > NODES - 2) ? (NODES - 2) : j);
    const float t = u - (float)j;          // ~[-0.5, 0.5]; edges extrapolate
    const float t2 = t * t;
    const float Gc = table[j] * (1.0f - t2)
                   + table[j - 1] * 0.5f * (t2 - t)
                   + table[j + 1] * 0.5f * (t2 + t);
    float val = Gc - wterm;

    // ---- block reduction (4 waves of 64) ----
    for (int off = 32; off > 0; off >>= 1) val += __shfl_down(val, off, 64);
    if (lane == 0) wsum[w] = val;
    __syncthreads();
    if (tid == 0) partial[n] = wsum[0] + wsum[1] + wsum[2] + wsum[3];
}

__global__ __launch_bounds__(256) void sigloss_reduce(const float* __restrict__ partial,
                                                      float* __restrict__ out) {
    const int tid = threadIdx.x;
    float v = 0.0f;
    #pragma unroll
    for (int i = tid; i < NROWS; i += 256) v += partial[i];
    for (int off = 32; off > 0; off >>= 1) v += __shfl_down(v, off, 64);
    __shared__ float wsum[4];
    if ((tid & 63) == 0) wsum[tid >> 6] = v;
    __syncthreads();
    if (tid == 0) out[0] = (wsum[0] + wsum[1] + wsum[2] + wsum[3]) * (1.0f / 65536.0f);
}

extern "C" void kernel_launch(void* const* d_in, const int* in_sizes, int n_in,
                              void* d_out, int out_size, void* d_ws, size_t ws_size,
                              hipStream_t stream) {
    const float* emb = (const float*)d_in[0];   // (64,256,64) f32
    float* partial = (float*)d_ws;              // 2048 floats scratch
    float* out = (float*)d_out;                 // 1 float
    sigloss_main<<<NROWS, 256, 0, stream>>>(emb, partial);
    sigloss_reduce<<<1, 256, 0, stream>>>(partial, out);
}

// Round 10
// 14.452 us; speedup vs baseline: 3.3805x; 1.0363x over previous
//
#include <hip/hip_runtime.h>

// SigmoidLoss: out = sum_n mean_{s,t} [ softplus(z) - W[s,t]*z ],  z = f1[n,s]*f2[n,t]
// f1[n,s] = emb[bi, s, ei], f2[n,s] = emb[32+bi, s, ei],  n = bi*64 + ei
// W banded: W[s,t] = 1-0.05q, q = (t>=s ? t-s : s-t-1), zero for q >= 20.
//
// G-table (8x work cut): G(c) = sum_s softplus(f1[s]*c) tabulated at 32 nodes
// on c in [-6,6]; each thread does one 3-point quadratic interpolation
// (err ~0.1 -> output bias << 32.6 threshold). Exact softplus in build:
// ln2*log2(1+exp2(x)), x clamped <= 14.5; ONE v_log_f32 per 8 elems.
// W-term via prefix sums P0 = sum f2, P1 = sum t*f2 (closed-form band).
//
// XCD swizzle: n = (blockIdx>>3) + (blockIdx&7)*256 (bijective). Blocks with
// consecutive n (same bi, neighboring ei) share staging cache lines (stride-
// 256B column reads); with round-robin XCD dispatch they'd scatter across 8
// XCD L2s (measured 16.4 MB FETCH vs 4.2 ideal). Swizzled, line-sharing
// blocks land on ONE XCD -> each line fetched ~once, later loads L2-hit.

#define SIDE 256
#define NB 32
#define NE 64
#define NROWS (NB * NE)  // 2048
#define LOG2E 1.4426950408889634f
#define LN2 0.6931471805599453f
#define NODES 32
#define CRANGE 6.0f
#define HSTEP (12.0f / 31.0f)
#define USCALE (31.0f / 12.0f)

__global__ __launch_bounds__(256) void sigloss_main(const float* __restrict__ emb,
                                                    float* __restrict__ partial) {
    const int n   = (blockIdx.x >> 3) + ((blockIdx.x & 7) << 8);  // XCD-local ei runs
    const int bi  = n >> 6;
    const int ei  = n & 63;
    const int tid = threadIdx.x;  // 0..255
    const int w   = tid >> 6;     // wave 0..3
    const int lane = tid & 63;

    // f1 in 8 part-blocks of 32, stride 36 (16B-aligned, bases in distinct banks).
    __shared__ __align__(16) float f1pad[8 * 36 - 4];  // 284
    __shared__ float P0arr[SIDE + 1];
    __shared__ float P1arr[SIDE + 1];
    __shared__ float table[NODES];
    __shared__ float wt0[4], wt1[4];
    __shared__ float wsum[4];

    const float a = emb[(size_t)bi * (SIDE * NE) + (size_t)tid * NE + ei];
    const float c = emb[(size_t)(NB + bi) * (SIDE * NE) + (size_t)tid * NE + ei];
    f1pad[36 * (tid >> 5) + (tid & 31)] = a;

    // ---- wave-level inclusive scans of f2 and t*f2 ----
    float v0 = c;
    float v1 = (float)tid * c;
    #pragma unroll
    for (int off = 1; off < 64; off <<= 1) {
        const float u0 = __shfl_up(v0, off, 64);
        const float u1 = __shfl_up(v1, off, 64);
        if (lane >= off) { v0 += u0; v1 += u1; }
    }
    if (lane == 63) { wt0[w] = v0; wt1[w] = v1; }
    __syncthreads();

    const float off0 = (w > 0 ? wt0[0] : 0.0f) + (w > 1 ? wt0[1] : 0.0f) + (w > 2 ? wt0[2] : 0.0f);
    const float off1 = (w > 0 ? wt1[0] : 0.0f) + (w > 1 ? wt1[1] : 0.0f) + (w > 2 ? wt1[2] : 0.0f);
    P0arr[tid + 1] = v0 + off0;
    P1arr[tid + 1] = v1 + off1;
    if (tid == 0) { P0arr[0] = 0.0f; P1arr[0] = 0.0f; }

    // ---- build G table: node = tid>>3 (32 nodes), part = tid&7 (32 s each) ----
    {
        const int node = tid >> 3;
        const int p    = tid & 7;
        const float ckl = (-CRANGE + (float)node * HSTEP) * LOG2E;
        const float4* fp = (const float4*)&f1pad[36 * p];
        float acc = 0.0f;
        #pragma unroll
        for (int i4 = 0; i4 < 8; i4 += 2) {
            const float4 A = fp[i4];
            const float4 B = fp[i4 + 1];
            const float e0 = __builtin_amdgcn_exp2f(fminf(A.x * ckl, 14.5f));
            const float e1 = __builtin_amdgcn_exp2f(fminf(A.y * ckl, 14.5f));
            const float e2 = __builtin_amdgcn_exp2f(fminf(A.z * ckl, 14.5f));
            const float e3 = __builtin_amdgcn_exp2f(fminf(A.w * ckl, 14.5f));
            const float e4 = __builtin_amdgcn_exp2f(fminf(B.x * ckl, 14.5f));
            const float e5 = __builtin_amdgcn_exp2f(fminf(B.y * ckl, 14.5f));
            const float e6 = __builtin_amdgcn_exp2f(fminf(B.z * ckl, 14.5f));
            const float e7 = __builtin_amdgcn_exp2f(fminf(B.w * ckl, 14.5f));
            const float p01 = (1.0f + e0) * (1.0f + e1);
            const float p23 = (1.0f + e2) * (1.0f + e3);
            const float p45 = (1.0f + e4) * (1.0f + e5);
            const float p67 = (1.0f + e6) * (1.0f + e7);
            acc += __builtin_amdgcn_logf((p01 * p23) * (p45 * p67));
        }
        acc += __shfl_xor(acc, 1, 64);
        acc += __shfl_xor(acc, 2, 64);
        acc += __shfl_xor(acc, 4, 64);
        if ((tid & 7) == 0) table[node] = acc * LN2;
    }
    __syncthreads();

    // ---- W-term for row s = tid via prefix sums ----
    const int s  = tid;
    const int t0 = (s - 20 > 0) ? (s - 20) : 0;
    const int t1 = (s + 20 < SIDE) ? (s + 20) : SIDE;
    const float P0t0 = P0arr[t0], P0s = P0arr[s], P0t1 = P0arr[t1];
    const float P1t0 = P1arr[t0], P1s = P1arr[s], P1t1 = P1arr[t1];
    const float sf = (float)s;
    const float left  = (1.05f - 0.05f * sf) * (P0s - P0t0) + 0.05f * (P1s - P1t0);
    const float right = (1.0f + 0.05f * sf) * (P0t1 - P0s) - 0.05f * (P1t1 - P1s);
    const float wterm = a * (left + right);

    // ---- G(c) by quadratic interpolation ----
    const float u = (c + CRANGE) * USCALE;
    int j = (int)floorf(u + 0.5f);
    j = (j < 1) ? 1 : ((j > NODES - 2) ? (NODES - 2) : j);
    const float t = u - (float)j;          // ~[-0.5, 0.5]; edges extrapolate
    const float t2 = t * t;
    const float Gc = table[j] * (1.0f - t2)
                   + table[j - 1] * 0.5f * (t2 - t)
                   + table[j + 1] * 0.5f * (t2 + t);
    float val = Gc - wterm;

    // ---- block reduction (4 waves of 64) ----
    for (int off = 32; off > 0; off >>= 1) val += __shfl_down(val, off, 64);
    if (lane == 0) wsum[w] = val;
    __syncthreads();
    if (tid == 0) partial[n] = wsum[0] + wsum[1] + wsum[2] + wsum[3];
}

__global__ __launch_bounds__(256) void sigloss_reduce(const float* __restrict__ partial,
                                                      float* __restrict__ out) {
    const int tid = threadIdx.x;
    float v = 0.0f;
    #pragma unroll
    for (int i = tid; i < NROWS; i += 256) v += partial[i];
    for (int off = 32; off > 0; off >>= 1) v += __shfl_down(v, off, 64);
    __shared__ float wsum[4];
    if ((tid & 63) == 0) wsum[tid >> 6] = v;
    __syncthreads();
    if (tid == 0) out[0] = (wsum[0] + wsum[1] + wsum[2] + wsum[3]) * (1.0f / 65536.0f);
}

extern "C" void kernel_launch(void* const* d_in, const int* in_sizes, int n_in,
                              void* d_out, int out_size, void* d_ws, size_t ws_size,
                              hipStream_t stream) {
    const float* emb = (const float*)d_in[0];   // (64,256,64) f32
    float* partial = (float*)d_ws;              // 2048 floats scratch
    float* out = (float*)d_out;                 // 1 float
    sigloss_main<<<NROWS, 256, 0, stream>>>(emb, partial);
    sigloss_reduce<<<1, 256, 0, stream>>>(partial, out);
}

// Round 11
// 12.915 us; speedup vs baseline: 3.7829x; 1.1191x over previous
//
#include <hip/hip_runtime.h>

// SigmoidLoss: out = sum_n mean_{s,t} [ softplus(z) - W[s,t]*z ],  z = f1[n,s]*f2[n,t]
// f1[n,s] = emb[bi, s, ei], f2[n,s] = emb[32+bi, s, ei],  n = bi*64 + ei
// W banded: W[s,t] = 1-0.05q, q = (t>=s ? t-s : s-t-1), zero for q >= 20.
//
// G-table (16x work cut vs direct): G(c) = sum_s softplus(f1[s]*c) tabulated
// at 16 nodes on c in [-6,6]; each thread does one 4-point CUBIC Lagrange
// interpolation (err ~0.3 worst-case per eval, sign-oscillating -> cancels;
// threshold 32.6). Exact softplus in build: ln2*log2(1+exp2(x)), x clamped
// <= 14.5; ONE v_log_f32 per 8 elems (8-factor product < 2^117 finite).
// W-term via prefix sums P0 = sum f2, P1 = sum t*f2 (closed-form band).
// XCD swizzle: n = (bid>>3)+(bid&7)*256 keeps line-sharing blocks on one XCD.

#define SIDE 256
#define NB 32
#define NE 64
#define NROWS (NB * NE)  // 2048
#define LOG2E 1.4426950408889634f
#define LN2 0.6931471805599453f
#define NODES 16
#define CRANGE 6.0f
#define HSTEP (12.0f / 15.0f)
#define USCALE (15.0f / 12.0f)

__global__ __launch_bounds__(256) void sigloss_main(const float* __restrict__ emb,
                                                    float* __restrict__ partial) {
    const int n   = (blockIdx.x >> 3) + ((blockIdx.x & 7) << 8);  // XCD-local ei runs
    const int bi  = n >> 6;
    const int ei  = n & 63;
    const int tid = threadIdx.x;  // 0..255
    const int w   = tid >> 6;     // wave 0..3
    const int lane = tid & 63;

    // f1 in 16 part-blocks of 16, stride 20 (80B: 16B-aligned bases; <=2-way
    // bank aliasing on the 16 distinct float4 addresses -> effectively free).
    __shared__ __align__(16) float f1pad[16 * 20];
    __shared__ float P0arr[SIDE + 1];
    __shared__ float P1arr[SIDE + 1];
    __shared__ float table[NODES];
    __shared__ float wt0[4], wt1[4];
    __shared__ float wsum[4];

    const float a = emb[(size_t)bi * (SIDE * NE) + (size_t)tid * NE + ei];
    const float c = emb[(size_t)(NB + bi) * (SIDE * NE) + (size_t)tid * NE + ei];
    f1pad[20 * (tid >> 4) + (tid & 15)] = a;

    // ---- wave-level inclusive scans of f2 and t*f2 ----
    float v0 = c;
    float v1 = (float)tid * c;
    #pragma unroll
    for (int off = 1; off < 64; off <<= 1) {
        const float u0 = __shfl_up(v0, off, 64);
        const float u1 = __shfl_up(v1, off, 64);
        if (lane >= off) { v0 += u0; v1 += u1; }
    }
    if (lane == 63) { wt0[w] = v0; wt1[w] = v1; }
    __syncthreads();

    const float off0 = (w > 0 ? wt0[0] : 0.0f) + (w > 1 ? wt0[1] : 0.0f) + (w > 2 ? wt0[2] : 0.0f);
    const float off1 = (w > 0 ? wt1[0] : 0.0f) + (w > 1 ? wt1[1] : 0.0f) + (w > 2 ? wt1[2] : 0.0f);
    P0arr[tid + 1] = v0 + off0;
    P1arr[tid + 1] = v1 + off1;
    if (tid == 0) { P0arr[0] = 0.0f; P1arr[0] = 0.0f; }

    // ---- build G table: node = tid>>4 (16 nodes), part = tid&15 (16 s each) ----
    {
        const int node = tid >> 4;
        const int p    = tid & 15;
        const float ckl = (-CRANGE + (float)node * HSTEP) * LOG2E;
        const float4* fp = (const float4*)&f1pad[20 * p];
        const float4 A = fp[0];
        const float4 B = fp[1];
        const float4 C = fp[2];
        const float4 D = fp[3];
        const float e0 = __builtin_amdgcn_exp2f(fminf(A.x * ckl, 14.5f));
        const float e1 = __builtin_amdgcn_exp2f(fminf(A.y * ckl, 14.5f));
        const float e2 = __builtin_amdgcn_exp2f(fminf(A.z * ckl, 14.5f));
        const float e3 = __builtin_amdgcn_exp2f(fminf(A.w * ckl, 14.5f));
        const float e4 = __builtin_amdgcn_exp2f(fminf(B.x * ckl, 14.5f));
        const float e5 = __builtin_amdgcn_exp2f(fminf(B.y * ckl, 14.5f));
        const float e6 = __builtin_amdgcn_exp2f(fminf(B.z * ckl, 14.5f));
        const float e7 = __builtin_amdgcn_exp2f(fminf(B.w * ckl, 14.5f));
        const float e8 = __builtin_amdgcn_exp2f(fminf(C.x * ckl, 14.5f));
        const float e9 = __builtin_amdgcn_exp2f(fminf(C.y * ckl, 14.5f));
        const float ea = __builtin_amdgcn_exp2f(fminf(C.z * ckl, 14.5f));
        const float eb = __builtin_amdgcn_exp2f(fminf(C.w * ckl, 14.5f));
        const float ec = __builtin_amdgcn_exp2f(fminf(D.x * ckl, 14.5f));
        const float ed = __builtin_amdgcn_exp2f(fminf(D.y * ckl, 14.5f));
        const float ee = __builtin_amdgcn_exp2f(fminf(D.z * ckl, 14.5f));
        const float ef = __builtin_amdgcn_exp2f(fminf(D.w * ckl, 14.5f));
        const float pA = ((1.0f + e0) * (1.0f + e1)) * ((1.0f + e2) * (1.0f + e3));
        const float pB = ((1.0f + e4) * (1.0f + e5)) * ((1.0f + e6) * (1.0f + e7));
        const float pC = ((1.0f + e8) * (1.0f + e9)) * ((1.0f + ea) * (1.0f + eb));
        const float pD = ((1.0f + ec) * (1.0f + ed)) * ((1.0f + ee) * (1.0f + ef));
        float acc = __builtin_amdgcn_logf(pA * pB) + __builtin_amdgcn_logf(pC * pD);
        acc += __shfl_xor(acc, 1, 64);
        acc += __shfl_xor(acc, 2, 64);
        acc += __shfl_xor(acc, 4, 64);
        acc += __shfl_xor(acc, 8, 64);
        if ((tid & 15) == 0) table[node] = acc * LN2;
    }
    __syncthreads();

    // ---- W-term for row s = tid via prefix sums ----
    const int s  = tid;
    const int t0 = (s - 20 > 0) ? (s - 20) : 0;
    const int t1 = (s + 20 < SIDE) ? (s + 20) : SIDE;
    const float P0t0 = P0arr[t0], P0s = P0arr[s], P0t1 = P0arr[t1];
    const float P1t0 = P1arr[t0], P1s = P1arr[s], P1t1 = P1arr[t1];
    const float sf = (float)s;
    const float left  = (1.05f - 0.05f * sf) * (P0s - P0t0) + 0.05f * (P1s - P1t0);
    const float right = (1.0f + 0.05f * sf) * (P0t1 - P0s) - 0.05f * (P1t1 - P1s);
    const float wterm = a * (left + right);

    // ---- G(c) by 4-point cubic Lagrange interpolation ----
    const float u = (c + CRANGE) * USCALE;
    int j = (int)floorf(u);
    j = (j < 1) ? 1 : ((j > NODES - 3) ? (NODES - 3) : j);
    const float t = u - (float)j;           // ~[0,1]; edges extrapolate mildly
    const float tm1 = t - 1.0f;
    const float tm2 = t - 2.0f;
    const float tp1 = t + 1.0f;
    const float w_m1 = -t * tm1 * tm2 * (1.0f / 6.0f);
    const float w_0  = tp1 * tm1 * tm2 * 0.5f;
    const float w_p1 = -t * tp1 * tm2 * 0.5f;
    const float w_p2 = t * tp1 * tm1 * (1.0f / 6.0f);
    const float Gc = table[j - 1] * w_m1 + table[j] * w_0
                   + table[j + 1] * w_p1 + table[j + 2] * w_p2;
    float val = Gc - wterm;

    // ---- block reduction (4 waves of 64) ----
    for (int off = 32; off > 0; off >>= 1) val += __shfl_down(val, off, 64);
    if (lane == 0) wsum[w] = val;
    __syncthreads();
    if (tid == 0) partial[n] = wsum[0] + wsum[1] + wsum[2] + wsum[3];
}

__global__ __launch_bounds__(64) void sigloss_reduce(const float* __restrict__ partial,
                                                     float* __restrict__ out) {
    const int lane = threadIdx.x;  // one wave
    const float4* p4 = (const float4*)partial;
    float v = 0.0f;
    #pragma unroll
    for (int i = 0; i < 8; ++i) {
        const float4 q = p4[lane + 64 * i];
        v += (q.x + q.y) + (q.z + q.w);
    }
    for (int off = 32; off > 0; off >>= 1) v += __shfl_down(v, off, 64);
    if (lane == 0) out[0] = v * (1.0f / 65536.0f);
}

extern "C" void kernel_launch(void* const* d_in, const int* in_sizes, int n_in,
                              void* d_out, int out_size, void* d_ws, size_t ws_size,
                              hipStream_t stream) {
    const float* emb = (const float*)d_in[0];   // (64,256,64) f32
    float* partial = (float*)d_ws;              // 2048 floats scratch
    float* out = (float*)d_out;                 // 1 float
    sigloss_main<<<NROWS, 256, 0, stream>>>(emb, partial);
    sigloss_reduce<<<1, 64, 0, stream>>>(partial, out);
}

// Round 12
// 11.513 us; speedup vs baseline: 4.2436x; 1.1218x over previous
//
#include <hip/hip_runtime.h>

// SigmoidLoss: out = sum_n mean_{s,t} [ softplus(z) - W[s,t]*z ],  z = f1[n,s]*f2[n,t]
// f1[n,s] = emb[bi, s, ei], f2[n,s] = emb[32+bi, s, ei],  n = bi*64 + ei
// W banded: W[s,t] = 1-0.05q, q = (t>=s ? t-s : s-t-1), zero for q >= 20.
//
// G-table: G_e(c) = sum_s softplus(f1[s]*c) at 16 nodes on [-6,6]; 4-point
// cubic Lagrange eval (same numerics as R11, absmax was 0.0).
// W-term via per-ei prefix sums P0 = sum f2, P1 = sum t*f2 (closed-form band).
//
// R12: block = (bi, 4 consecutive ei), 512 blocks x 512 threads. Staging is
// ONE float4 per thread (the 4-ei chunk of one s-row, 16B aligned): 16 useful
// bytes per L1 transaction instead of 4 -> per-CU staging transactions drop
// 4096 -> 1024 (TA serialization was the ~7 us residual). Waves 0-3 scan f2
// (per-ei) CONCURRENTLY with waves 4-7 building the 4 G-tables.

#define SIDE 256
#define NB 32
#define NE 64
#define NBLK 512          // 32 bi x 16 ei-groups
#define LOG2E 1.4426950408889634f
#define LN2 0.6931471805599453f
#define NODES 16
#define CRANGE 6.0f
#define HSTEP (12.0f / 15.0f)
#define USCALE (15.0f / 12.0f)

__global__ __launch_bounds__(512) void sigloss_main(const float* __restrict__ emb,
                                                    float* __restrict__ partial) {
    const int bid  = blockIdx.x;
    const int g    = (bid >> 3) + ((bid & 7) << 6);  // XCD swizzle (bijective on 512)
    const int bi   = g >> 4;
    const int ei0  = (g & 15) << 2;
    const int tid  = threadIdx.x;   // 0..511
    const int wv   = tid >> 6;      // wave 0..7
    const int lane = tid & 63;

    // f1 part-padded: 8 blocks of 32 s, stride 36 (16B-aligned, distinct banks)
    __shared__ __align__(16) float f1p[4][8 * 36];
    __shared__ float f2s[4][SIDE + 4];
    __shared__ float P0[4][SIDE + 1];
    __shared__ float P1[4][SIDE + 1];
    __shared__ float table[4][NODES + 2];
    __shared__ float wsum[8];

    // ---- staging: one float4 (4 ei) per thread ----
    {
        const int half = tid >> 8;          // 0: f1, 1: f2
        const int s    = tid & 255;
        const float4 v = *(const float4*)(emb
            + (size_t)(half ? NB + bi : bi) * (SIDE * NE) + (size_t)s * NE + ei0);
        if (half == 0) {
            const int idx = ((s >> 5) * 36) + (s & 31);
            f1p[0][idx] = v.x; f1p[1][idx] = v.y; f1p[2][idx] = v.z; f1p[3][idx] = v.w;
        } else {
            f2s[0][s] = v.x; f2s[1][s] = v.y; f2s[2][s] = v.z; f2s[3][s] = v.w;
        }
    }
    __syncthreads();

    if (wv < 4) {
        // ---- waves 0-3: per-ei inclusive scans of f2 and t*f2 ----
        const int e = wv;
        float c0 = 0.0f, c1 = 0.0f;
        if (lane == 0) { P0[e][0] = 0.0f; P1[e][0] = 0.0f; }
        #pragma unroll
        for (int ch = 0; ch < 4; ++ch) {
            const int t = ch * 64 + lane;
            float v0 = f2s[e][t];
            float v1 = (float)t * v0;
            #pragma unroll
            for (int off = 1; off < 64; off <<= 1) {
                const float u0 = __shfl_up(v0, off, 64);
                const float u1 = __shfl_up(v1, off, 64);
                if (lane >= off) { v0 += u0; v1 += u1; }
            }
            P0[e][t + 1] = v0 + c0;
            P1[e][t + 1] = v1 + c1;
            c0 += __shfl(v0, 63, 64);
            c1 += __shfl(v1, 63, 64);
        }
    } else {
        // ---- waves 4-7: build G table for e = wv-4 ----
        // node = lane>>2 (16 nodes), part = lane&3 (4 parts x 64 s)
        const int e    = wv - 4;
        const int node = lane >> 2;
        const int p    = lane & 3;
        const float ck = (-CRANGE + (float)node * HSTEP) * LOG2E;
        float acc = 0.0f;
        #pragma unroll
        for (int blk = 0; blk < 2; ++blk) {
            const float4* fp = (const float4*)&f1p[e][(2 * p + blk) * 36];
            #pragma unroll
            for (int i4 = 0; i4 < 8; i4 += 2) {
                const float4 A = fp[i4];
                const float4 B = fp[i4 + 1];
                const float e0 = __builtin_amdgcn_exp2f(fminf(A.x * ck, 14.5f));
                const float e1 = __builtin_amdgcn_exp2f(fminf(A.y * ck, 14.5f));
                const float e2 = __builtin_amdgcn_exp2f(fminf(A.z * ck, 14.5f));
                const float e3 = __builtin_amdgcn_exp2f(fminf(A.w * ck, 14.5f));
                const float e4 = __builtin_amdgcn_exp2f(fminf(B.x * ck, 14.5f));
                const float e5 = __builtin_amdgcn_exp2f(fminf(B.y * ck, 14.5f));
                const float e6 = __builtin_amdgcn_exp2f(fminf(B.z * ck, 14.5f));
                const float e7 = __builtin_amdgcn_exp2f(fminf(B.w * ck, 14.5f));
                const float p01 = (1.0f + e0) * (1.0f + e1);
                const float p23 = (1.0f + e2) * (1.0f + e3);
                const float p45 = (1.0f + e4) * (1.0f + e5);
                const float p67 = (1.0f + e6) * (1.0f + e7);
                acc += __builtin_amdgcn_logf((p01 * p23) * (p45 * p67));
            }
        }
        acc += __shfl_xor(acc, 1, 64);
        acc += __shfl_xor(acc, 2, 64);
        if (p == 0) table[e][node] = acc * LN2;
    }
    __syncthreads();

    // ---- eval: e = tid>>7, t in {tb, tb+128} ----
    const int e  = tid >> 7;
    const int tb = tid & 127;
    float val = 0.0f;
    #pragma unroll
    for (int r = 0; r < 2; ++r) {
        const int t = tb + (r << 7);
        const float c = f2s[e][t];

        // cubic interpolation of G_e at c
        const float u = (c + CRANGE) * USCALE;
        int j = (int)floorf(u);
        j = (j < 1) ? 1 : ((j > NODES - 3) ? (NODES - 3) : j);
        const float tt  = u - (float)j;
        const float tm1 = tt - 1.0f;
        const float tm2 = tt - 2.0f;
        const float tp1 = tt + 1.0f;
        const float w_m1 = -tt * tm1 * tm2 * (1.0f / 6.0f);
        const float w_0  = tp1 * tm1 * tm2 * 0.5f;
        const float w_p1 = -tt * tp1 * tm2 * 0.5f;
        const float w_p2 = tt * tp1 * tm1 * (1.0f / 6.0f);
        const float Gc = table[e][j - 1] * w_m1 + table[e][j] * w_0
                       + table[e][j + 1] * w_p1 + table[e][j + 2] * w_p2;

        // W-term for row s = t
        const int s  = t;
        const int t0 = (s - 20 > 0) ? (s - 20) : 0;
        const int t1 = (s + 20 < SIDE) ? (s + 20) : SIDE;
        const float a = f1p[e][((s >> 5) * 36) + (s & 31)];
        const float P0t0 = P0[e][t0], P0s = P0[e][s], P0t1 = P0[e][t1];
        const float P1t0 = P1[e][t0], P1s = P1[e][s], P1t1 = P1[e][t1];
        const float sf = (float)s;
        const float left  = (1.05f - 0.05f * sf) * (P0s - P0t0) + 0.05f * (P1s - P1t0);
        const float right = (1.0f + 0.05f * sf) * (P0t1 - P0s) - 0.05f * (P1t1 - P1s);
        val += Gc - a * (left + right);
    }

    // ---- block reduction (8 waves) ----
    for (int off = 32; off > 0; off >>= 1) val += __shfl_down(val, off, 64);
    if (lane == 0) wsum[wv] = val;
    __syncthreads();
    if (tid == 0) {
        float b0 = (wsum[0] + wsum[1]) + (wsum[2] + wsum[3]);
        float b1 = (wsum[4] + wsum[5]) + (wsum[6] + wsum[7]);
        partial[bid] = b0 + b1;
    }
}

__global__ __launch_bounds__(64) void sigloss_reduce(const float* __restrict__ partial,
                                                     float* __restrict__ out) {
    const int lane = threadIdx.x;  // one wave
    const float4* p4 = (const float4*)partial;   // 128 float4
    const float4 q0 = p4[lane];
    const float4 q1 = p4[lane + 64];
    float v = ((q0.x + q0.y) + (q0.z + q0.w)) + ((q1.x + q1.y) + (q1.z + q1.w));
    for (int off = 32; off > 0; off >>= 1) v += __shfl_down(v, off, 64);
    if (lane == 0) out[0] = v * (1.0f / 65536.0f);
}

extern "C" void kernel_launch(void* const* d_in, const int* in_sizes, int n_in,
                              void* d_out, int out_size, void* d_ws, size_t ws_size,
                              hipStream_t stream) {
    const float* emb = (const float*)d_in[0];   // (64,256,64) f32
    float* partial = (float*)d_ws;              // 512 floats scratch
    float* out = (float*)d_out;                 // 1 float
    sigloss_main<<<NBLK, 512, 0, stream>>>(emb, partial);
    sigloss_reduce<<<1, 64, 0, stream>>>(partial, out);
}